// Round 2
// baseline (51.620 us; speedup 1.0000x reference)
//
#include <hip/hip_runtime.h>
#include <math.h>

#define NEG_INF (-1.0e9f)
#define EPSF (1e-8f)

using f32x4 = __attribute__((ext_vector_type(4))) float;

__device__ __forceinline__ float n2n(float x) {
    // nan_to_num(nan=0, posinf=0, neginf=0)
    return isfinite(x) ? x : 0.0f;
}

__device__ __forceinline__ float tanh_fast(float x) {
    float xc = fminf(fmaxf(x, -20.0f), 20.0f);
    float t = __expf(2.0f * xc);
    return (t - 1.0f) / (t + 1.0f);
}

// One block per batch row. 256 threads = 4 waves. N=1024, F=8.
// Element n's 8 floats = two float4s: lo (x0..x3) at f=2n, hi (x4..x7) at f=2n+1.
// Lane parity picks the half: even lanes process lo-halves (terms t1,t2,t5),
// odd lanes process hi-halves (terms t3,t4). Each lane loads ONE contiguous
// float4 per iteration -> perfectly coalesced 1KB/wave-instruction.
__global__ __launch_bounds__(256) void setdsr_kernel(
    const float* __restrict__ X, const float* __restrict__ mask,
    float* __restrict__ out)
{
    const int b = blockIdx.x;
    const int tid = threadIdx.x;

    const f32x4* __restrict__ X4 =
        reinterpret_cast<const f32x4*>(X + (size_t)b * 8192);
    const float* __restrict__ Mr = mask + (size_t)b * 1024;

    const bool lo_lane = (tid & 1) == 0;

    float s1 = 0.f;          // sum((x0*x1)^2 * m)        [even lanes]
    float s2 = 0.f;          // sum((safelog+tanh) * m)   [even lanes]
    float sm = 0.f;          // sum(m)                    [even lanes]
    float svw = 0.f;         // sum(v*w)                  [odd lanes]
    float sw = 0.f;          // sum(w)                    [odd lanes]
    float mx5 = NEG_INF;     // max(sin*cos masked)       [even lanes]
    float e3[8];             // lse scores                [odd lanes]

    #pragma unroll
    for (int ph = 0; ph < 2; ++ph) {
        f32x4 v[4];
        float mk[4];
        #pragma unroll
        for (int j = 0; j < 4; ++j) {
            int f = tid + (ph * 4 + j) * 256;   // float4 index in row
            v[j] = __builtin_nontemporal_load(&X4[f]);
            mk[j] = __builtin_nontemporal_load(&Mr[f >> 1]);
        }
        if (lo_lane) {
            #pragma unroll
            for (int j = 0; j < 4; ++j) {
                float x0 = v[j].x, x1 = v[j].y, x2 = v[j].z, x3 = v[j].w;
                float m = mk[j];
                float p = x0 * x1;
                s1 += p * p * m;
                s2 += (__logf(fabsf(x2) + EPSF) + tanh_fast(x3)) * m;
                sm += m;
                float t5 = __sinf(x0) * __cosf(x1);
                mx5 = fmaxf(mx5, (m > 0.f) ? t5 : NEG_INF);
            }
        } else {
            #pragma unroll
            for (int j = 0; j < 4; ++j) {
                float x4 = v[j].x, x5 = v[j].y, x6 = v[j].z, x7 = v[j].w;
                float m = mk[j];
                e3[ph * 4 + j] = (m > 0.f) ? (x4 - x5) : NEG_INF;
                float w = n2n(fabsf(x7)) * m;
                svw += n2n(x6) * w;
                sw += w;
            }
        }
    }

    // Deferred per-thread LSE over the 8 register-held scores (odd lanes).
    float m3 = NEG_INF, s3 = 0.f;
    if (!lo_lane) {
        m3 = e3[0];
        #pragma unroll
        for (int j = 1; j < 8; ++j) m3 = fmaxf(m3, e3[j]);
        #pragma unroll
        for (int j = 0; j < 8; ++j) s3 += __expf(e3[j] - m3);
    }

    // Wave-64 butterfly reduction (all 8 partials; identities on non-owner lanes).
    #pragma unroll
    for (int off = 32; off > 0; off >>= 1) {
        s1  += __shfl_xor(s1, off);
        s2  += __shfl_xor(s2, off);
        sm  += __shfl_xor(sm, off);
        svw += __shfl_xor(svw, off);
        sw  += __shfl_xor(sw, off);
        mx5 = fmaxf(mx5, __shfl_xor(mx5, off));
        float m3o = __shfl_xor(m3, off);
        float s3o = __shfl_xor(s3, off);
        float M = fmaxf(m3, m3o);
        s3 = s3 * __expf(m3 - M) + s3o * __expf(m3o - M);
        m3 = M;
    }

    // Cross-wave merge via tiny LDS (4 waves x 8 partials).
    __shared__ float red[4][8];
    int wave = tid >> 6;
    if ((tid & 63) == 0) {
        red[wave][0] = s1;  red[wave][1] = s2;  red[wave][2] = sm;
        red[wave][3] = svw; red[wave][4] = sw;  red[wave][5] = mx5;
        red[wave][6] = m3;  red[wave][7] = s3;
    }
    __syncthreads();
    if (tid == 0) {
        float S1 = red[0][0], S2 = red[0][1], SM = red[0][2];
        float SVW = red[0][3], SW = red[0][4], MX = red[0][5];
        float M3 = red[0][6], S3 = red[0][7];
        #pragma unroll
        for (int w2 = 1; w2 < 4; ++w2) {
            S1  += red[w2][0];
            S2  += red[w2][1];
            SM  += red[w2][2];
            SVW += red[w2][3];
            SW  += red[w2][4];
            MX = fmaxf(MX, red[w2][5]);
            float m2 = red[w2][6], sx = red[w2][7];
            float M = fmaxf(M3, m2);
            S3 = S3 * __expf(M3 - M) + sx * __expf(m2 - M);
            M3 = M;
        }
        float t1 = S1;
        float t2 = S2 / (SM + EPSF);
        float t3 = __logf(S3) + M3;
        float t4 = SVW / (SW + EPSF);
        float t5 = MX;
        out[b] = t1 + t2 + t3 + t4 + t5;
    }
}

extern "C" void kernel_launch(void* const* d_in, const int* in_sizes, int n_in,
                              void* d_out, int out_size, void* d_ws, size_t ws_size,
                              hipStream_t stream) {
    const float* X = (const float*)d_in[0];       // (8192, 1024, 8) f32
    const float* mask = (const float*)d_in[1];    // (8192, 1024) f32
    float* out = (float*)d_out;                   // (8192,) f32
    int B = out_size;                             // 8192
    setdsr_kernel<<<B, 256, 0, stream>>>(X, mask, out);
}